// Round 7
// baseline (497.576 us; speedup 1.0000x reference)
//
#include <hip/hip_runtime.h>
#include <hip/hip_bf16.h>
#include <stdint.h>

typedef unsigned short u16;
typedef __attribute__((ext_vector_type(8))) short bf16x8;
typedef __attribute__((ext_vector_type(4))) float f32x4;

#define S_LEN 577
#define DMODEL 768
#define NHEAD 12
#define DH 64
#define BATCH 16
#define M_ROWS (BATCH * S_LEN)   /* 9232 */
#define M_PAD 9344               /* 73 * 128 */
#define VT_STRIDE 640            /* padded S so 16B frag loads stay aligned */

__device__ __forceinline__ u16 f2bu(float f) {
  uint32_t u = __float_as_uint(f);
  u += 0x7FFFu + ((u >> 16) & 1u);      // RNE; inputs are finite
  return (u16)(u >> 16);
}
__device__ __forceinline__ float bu2f(u16 b) {
  return __uint_as_float(((uint32_t)b) << 16);
}
// async global->LDS, 16B per lane; LDS dest = wave-uniform base + lane*16
__device__ __forceinline__ void gl2lds16(const u16* g, u16* l) {
  __builtin_amdgcn_global_load_lds(
      (const __attribute__((address_space(1))) unsigned int*)g,
      (__attribute__((address_space(3))) unsigned int*)l, 16, 0, 0);
}

// ---------------- prep: x fp32 -> bf16 [M_PAD,768], pad rows zeroed ----------
__global__ __launch_bounds__(256) void prep_x(const float* __restrict__ x,
                                              u16* __restrict__ xb) {
  int e = (blockIdx.x * 256 + threadIdx.x) * 8;
  u16 o[8];
  if (e < M_ROWS * DMODEL) {
    float4 f0 = *(const float4*)(x + e);
    float4 f1 = *(const float4*)(x + e + 4);
    o[0] = f2bu(f0.x); o[1] = f2bu(f0.y); o[2] = f2bu(f0.z); o[3] = f2bu(f0.w);
    o[4] = f2bu(f1.x); o[5] = f2bu(f1.y); o[6] = f2bu(f1.z); o[7] = f2bu(f1.w);
  } else {
#pragma unroll
    for (int i = 0; i < 8; ++i) o[i] = 0;
  }
  *(uint4*)(xb + e) = *(const uint4*)o;
}

// ------------- prep: weights fp32 [K,N] -> bf16 transposed [N,K], tiled ------
// wtqkv rows: [0,1536)=Wq^T, [1536,3072)=Wk^T, [3072,3840)=Wv^T ; wot = Wo^T
__global__ __launch_bounds__(256) void prep_w(
    const float* __restrict__ Wq, const float* __restrict__ Wk,
    const float* __restrict__ Wv, const float* __restrict__ Wo,
    u16* __restrict__ wtqkv, u16* __restrict__ wot) {
  __shared__ u16 tile[32][33];
  int blk = blockIdx.x;
  const float* W; int N; u16* dst; int rowbase;
  if (blk < 1152)      { W = Wq; N = 1536; dst = wtqkv; rowbase = 0; }
  else if (blk < 2304) { W = Wk; N = 1536; dst = wtqkv; rowbase = 1536; blk -= 1152; }
  else if (blk < 2880) { W = Wv; N = 768;  dst = wtqkv; rowbase = 3072; blk -= 2304; }
  else                 { W = Wo; N = 768;  dst = wot;   rowbase = 0;    blk -= 2880; }
  const int ntiles = N >> 5;
  const int tk = blk / ntiles, tn = blk - tk * ntiles;
  const int c = threadIdx.x & 31, r0 = threadIdx.x >> 5;
#pragma unroll
  for (int i = 0; i < 4; ++i) {
    int r = i * 8 + r0;
    tile[r][c] = f2bu(W[(size_t)(tk * 32 + r) * N + tn * 32 + c]);
  }
  __syncthreads();
#pragma unroll
  for (int i = 0; i < 4; ++i) {
    int r = i * 8 + r0;
    dst[(size_t)(rowbase + tn * 32 + r) * 768 + tk * 32 + c] = tile[c][r];
  }
}

// ---------------- bf16 MFMA GEMM: C[M,N] = A[M,768] * Bt[N,768]^T ------------
// m97 structure: global_load_lds width-16 staging into unpadded 128x32 tiles.
// mode 0: out fp32 [M_ROWS,N] + biasO[n]  (output projection)
// mode 1: scatter -> q1/q2/k1/k2 [B,H,S,64] bf16, v -> vt [B,H,64,640]
__global__ __launch_bounds__(256, 2) void gemm_bf16(
    const u16* __restrict__ A, const u16* __restrict__ Bt, int N, int mode,
    float* __restrict__ outF, const float* __restrict__ biasO,
    u16* __restrict__ q1p, u16* __restrict__ q2p,
    u16* __restrict__ k1p, u16* __restrict__ k2p, u16* __restrict__ vtp,
    const float* __restrict__ bq, const float* __restrict__ bk,
    const float* __restrict__ bvp) {
  __shared__ u16 lA[128 * 32];
  __shared__ u16 lB[128 * 32];
  const int t = threadIdx.x;
  const int lane = t & 63, wave = t >> 6;
  const int quad = lane >> 4, l16 = lane & 15;
  const int wm = wave & 1, wn = wave >> 1;
  const int m0 = blockIdx.x * 128;
  const int n0 = blockIdx.y * 128;

  f32x4 zero = {0.f, 0.f, 0.f, 0.f};
  f32x4 acc[4][4];
  for (int i = 0; i < 4; ++i) for (int j = 0; j < 4; ++j) acc[i][j] = zero;

  // staging: wave w owns rows w*32..w*32+31 (2 chunks of 16 rows);
  // lane -> row base + lane/4, col (lane%4)*8  (LDS offset == lane*16 B)
  const int srow = wave * 32 + (lane >> 2);
  const int scol = (lane & 3) * 8;
  const u16* gA = A + (size_t)(m0 + srow) * 768 + scol;
  const u16* gB = Bt + (size_t)(n0 + srow) * 768 + scol;
  u16* sA = lA + wave * 1024;   // wave-uniform LDS base
  u16* sB = lB + wave * 1024;

  for (int k0 = 0; k0 < 768; k0 += 32) {
    gl2lds16(gA + k0, sA);
    gl2lds16(gA + k0 + 16 * 768, sA + 512);
    gl2lds16(gB + k0, sB);
    gl2lds16(gB + k0 + 16 * 768, sB + 512);
    __syncthreads();
    bf16x8 af[4], bfr[4];
#pragma unroll
    for (int i = 0; i < 4; ++i)
      af[i] = *(const bf16x8*)(lA + (wm * 64 + i * 16 + l16) * 32 + quad * 8);
#pragma unroll
    for (int j = 0; j < 4; ++j)
      bfr[j] = *(const bf16x8*)(lB + (wn * 64 + j * 16 + l16) * 32 + quad * 8);
#pragma unroll
    for (int i = 0; i < 4; ++i)
#pragma unroll
      for (int j = 0; j < 4; ++j)
        acc[i][j] = __builtin_amdgcn_mfma_f32_16x16x32_bf16(af[i], bfr[j], acc[i][j], 0, 0, 0);
    __syncthreads();
  }

#pragma unroll
  for (int i = 0; i < 4; ++i) {
#pragma unroll
    for (int j = 0; j < 4; ++j) {
      int n = n0 + wn * 64 + j * 16 + l16;
#pragma unroll
      for (int r = 0; r < 4; ++r) {
        int m = m0 + wm * 64 + i * 16 + quad * 4 + r;
        if (m >= M_ROWS) continue;
        float v = acc[i][j][r];
        if (mode == 0) {
          outF[(size_t)m * N + n] = v + biasO[n];
        } else {
          int b = m / 577;
          int s = m - b * 577;
          if (n < 1536) {
            int ch = (n < 768) ? n : (n - 768);
            u16* dst = (n < 768) ? q1p : q2p;
            dst[(((size_t)b * 12 + (ch >> 6)) * 577 + s) * 64 + (ch & 63)] = f2bu(v + bq[n]);
          } else if (n < 3072) {
            int nn = n - 1536;
            int ch = (nn < 768) ? nn : (nn - 768);
            u16* dst = (nn < 768) ? k1p : k2p;
            dst[(((size_t)b * 12 + (ch >> 6)) * 577 + s) * 64 + (ch & 63)] = f2bu(v + bk[nn]);
          } else {
            int ch = n - 3072;
            vtp[(((size_t)b * 12 + (ch >> 6)) * 64 + (ch & 63)) * VT_STRIDE + s] = f2bu(v + bvp[ch]);
          }
        }
      }
    }
  }
}

// ---------------- flash-style differential attention (no-max softmax) --------
// 64 KV rows per iteration: all 16 K-frag loads batched at loop top (deep
// memory pipeline), both halves' QK MFMAs back-to-back, half0 exp/PV overlaps
// half1 in the scheduler. grid: (bh=192, qblock=10); 4 waves x 16 q-rows.
__global__ __launch_bounds__(256, 2) void attn(
    const u16* __restrict__ q1, const u16* __restrict__ q2,
    const u16* __restrict__ k1, const u16* __restrict__ k2,
    const u16* __restrict__ vt, u16* __restrict__ ctx_t,
    const float* __restrict__ lam_p) {
  __shared__ u16 pls[4][2][16 * 40];   // per-wave P staging (D-layout -> A-layout)
  const int bh = blockIdx.x;
  const int qb = blockIdx.y;
  const int lane = threadIdx.x & 63, wave = threadIdx.x >> 6;
  const int quad = lane >> 4, l16 = lane & 15;
  const int q0 = qb * 64 + wave * 16;
  if (q0 >= S_LEN) return;

  const float lam = lam_p[0];
  const float CEXP = 0.125f * 1.44269504f;   // scale * log2(e), folded
  const size_t qkbase = (size_t)bh * S_LEN * DH;

  int qr = q0 + l16; if (qr > 576) qr = 576;   // clamp tail (results discarded)
  bf16x8 q1f[2], q2f[2];
#pragma unroll
  for (int c = 0; c < 2; ++c) {
    q1f[c] = *(const bf16x8*)(q1 + qkbase + (size_t)qr * 64 + c * 32 + quad * 8);
    q2f[c] = *(const bf16x8*)(q2 + qkbase + (size_t)qr * 64 + c * 32 + quad * 8);
  }

  f32x4 zero = {0.f, 0.f, 0.f, 0.f};
  f32x4 O1[4], O2[4];
  float l1[4], l2[4];
#pragma unroll
  for (int i = 0; i < 4; ++i) { O1[i] = zero; O2[i] = zero; l1[i] = 0.f; l2[i] = 0.f; }

  u16* p1w = &pls[wave][0][0];
  u16* p2w = &pls[wave][1][0];
  const size_t vbase = (size_t)bh * 64 * VT_STRIDE;

  for (int kb = 0; kb < 10; ++kb) {
    const int kv0 = kb * 64;
    // --- batched K loads for both 32-row halves (16 loads in flight) ---
    bf16x8 k1f[4][2], k2f[4][2];
#pragma unroll
    for (int tt = 0; tt < 4; ++tt) {
      int kr = kv0 + tt * 16 + l16; if (kr > 576) kr = 576;
      size_t off = qkbase + (size_t)kr * 64 + quad * 8;
      k1f[tt][0] = *(const bf16x8*)(k1 + off);
      k1f[tt][1] = *(const bf16x8*)(k1 + off + 32);
      k2f[tt][0] = *(const bf16x8*)(k2 + off);
      k2f[tt][1] = *(const bf16x8*)(k2 + off + 32);
    }
    // --- all QK MFMAs for the 64 kv rows ---
    f32x4 s1[4], s2[4];
#pragma unroll
    for (int tt = 0; tt < 4; ++tt) {
      s1[tt] = __builtin_amdgcn_mfma_f32_16x16x32_bf16(q1f[0], k1f[tt][0], zero, 0, 0, 0);
      s1[tt] = __builtin_amdgcn_mfma_f32_16x16x32_bf16(q1f[1], k1f[tt][1], s1[tt], 0, 0, 0);
      s2[tt] = __builtin_amdgcn_mfma_f32_16x16x32_bf16(q2f[0], k2f[tt][0], zero, 0, 0, 0);
      s2[tt] = __builtin_amdgcn_mfma_f32_16x16x32_bf16(q2f[1], k2f[tt][1], s2[tt], 0, 0, 0);
    }
    // --- per 32-row half: exp -> P pack -> PV (halves overlap in scheduler) ---
#pragma unroll
    for (int h = 0; h < 2; ++h) {
      bf16x8 vf[4];
#pragma unroll
      for (int tt = 0; tt < 4; ++tt)
        vf[tt] = *(const bf16x8*)(vt + vbase + (size_t)(tt * 16 + l16) * VT_STRIDE + kv0 + h * 32 + quad * 8);
      const int t0 = h * 2, t1 = h * 2 + 1;
      bool ok0 = (kv0 + h * 32 + l16) < S_LEN;
      bool ok1 = (kv0 + h * 32 + 16 + l16) < S_LEN;
#pragma unroll
      for (int i = 0; i < 4; ++i) {
        float p10 = ok0 ? exp2f(s1[t0][i] * CEXP) : 0.f;
        float p11 = ok1 ? exp2f(s1[t1][i] * CEXP) : 0.f;
        float p20 = ok0 ? exp2f(s2[t0][i] * CEXP) : 0.f;
        float p21 = ok1 ? exp2f(s2[t1][i] * CEXP) : 0.f;
        l1[i] += p10 + p11;
        l2[i] += p20 + p21;
        // truncating bf16 convert (cheap; ~0.1% bias, well under budget)
        p1w[(quad * 4 + i) * 40 + l16]      = (u16)(__float_as_uint(p10) >> 16);
        p1w[(quad * 4 + i) * 40 + l16 + 16] = (u16)(__float_as_uint(p11) >> 16);
        p2w[(quad * 4 + i) * 40 + l16]      = (u16)(__float_as_uint(p20) >> 16);
        p2w[(quad * 4 + i) * 40 + l16 + 16] = (u16)(__float_as_uint(p21) >> 16);
      }
      bf16x8 p1a = *(const bf16x8*)(p1w + l16 * 40 + quad * 8);
      bf16x8 p2a = *(const bf16x8*)(p2w + l16 * 40 + quad * 8);
#pragma unroll
      for (int tt = 0; tt < 4; ++tt) {
        O1[tt] = __builtin_amdgcn_mfma_f32_16x16x32_bf16(p1a, vf[tt], O1[tt], 0, 0, 0);
        O2[tt] = __builtin_amdgcn_mfma_f32_16x16x32_bf16(p2a, vf[tt], O2[tt], 0, 0, 0);
      }
    }
  }
  // reduce partial row-sums across the quad's 16 lanes
#pragma unroll
  for (int d = 1; d < 16; d <<= 1)
#pragma unroll
    for (int i = 0; i < 4; ++i) {
      l1[i] += __shfl_xor(l1[i], d);
      l2[i] += __shfl_xor(l2[i], d);
    }
  float inv1[4], inv2[4];
#pragma unroll
  for (int i = 0; i < 4; ++i) { inv1[i] = 1.f / l1[i]; inv2[i] = 1.f / l2[i]; }
#pragma unroll
  for (int tt = 0; tt < 4; ++tt) {
    size_t cb = ((size_t)bh * 64 + tt * 16 + l16) * S_LEN;
#pragma unroll
    for (int i = 0; i < 4; ++i) {
      int s = q0 + quad * 4 + i;
      if (s < S_LEN)
        ctx_t[cb + s] = f2bu(O1[tt][i] * inv1[i] - lam * O2[tt][i] * inv2[i]);
    }
  }
}

// ---------------- GroupNorm over (b,h): Dh*S elements, then affine ----------
// ctx_t [B,H,64,S] -> context flat [B][D*S] (== reference's reinterpret trick)
__global__ __launch_bounds__(256) void gnorm(
    const u16* __restrict__ ctx_t, u16* __restrict__ context,
    const float* __restrict__ gw, const float* __restrict__ gb) {
  const int bh = blockIdx.x;
  const int h = bh % 12;
  const int NEL = 64 * S_LEN;          // 36928
  const int NV = NEL / 8;              // 4616
  const u16* src = ctx_t + (size_t)bh * NEL;
  float sum = 0.f, sq = 0.f;
  for (int v = threadIdx.x; v < NV; v += 256) {
    uint4 raw = *(const uint4*)(src + v * 8);
    uint32_t w[4] = {raw.x, raw.y, raw.z, raw.w};
#pragma unroll
    for (int j = 0; j < 4; ++j) {
      float f0 = bu2f((u16)(w[j] & 0xffff));
      float f1 = bu2f((u16)(w[j] >> 16));
      sum += f0 + f1; sq += f0 * f0 + f1 * f1;
    }
  }
#pragma unroll
  for (int d = 1; d < 64; d <<= 1) {
    sum += __shfl_xor(sum, d);
    sq += __shfl_xor(sq, d);
  }
  __shared__ float rs[4], rq[4];
  __shared__ float wv[64], bv2[64];
  int wave = threadIdx.x >> 6;
  if ((threadIdx.x & 63) == 0) { rs[wave] = sum; rq[wave] = sq; }
  __syncthreads();
  float ts = rs[0] + rs[1] + rs[2] + rs[3];
  float tq = rq[0] + rq[1] + rq[2] + rq[3];
  const float Ninv = 1.0f / (float)NEL;
  float mu = ts * Ninv;
  float var = tq * Ninv - mu * mu;
  float rstd = rsqrtf(var + 1e-5f);
  if (threadIdx.x < 64) {
    float w = gw[h * 64 + threadIdx.x] * rstd;
    wv[threadIdx.x] = w;
    bv2[threadIdx.x] = gb[h * 64 + threadIdx.x] - mu * w;
  }
  __syncthreads();
  u16* dst = context + (size_t)bh * NEL;   // b*(768*577) + h*(64*577)
  for (int v = threadIdx.x; v < NV; v += 256) {
    uint4 raw = *(const uint4*)(src + v * 8);
    uint32_t w[4] = {raw.x, raw.y, raw.z, raw.w};
    int base = v * 8;
    int d0 = base / 577;
    int r0 = base - d0 * 577;
    u16 o[8];
#pragma unroll
    for (int j = 0; j < 4; ++j) {
#pragma unroll
      for (int e = 0; e < 2; ++e) {
        int ii = j * 2 + e;
        int dd = (r0 + ii >= 577) ? d0 + 1 : d0;
        float f = bu2f((u16)(e == 0 ? (w[j] & 0xffff) : (w[j] >> 16)));
        o[ii] = f2bu(f * wv[dd] + bv2[dd]);
      }
    }
    *(uint4*)(dst + base) = *(const uint4*)o;
  }
}

extern "C" void kernel_launch(void* const* d_in, const int* in_sizes, int n_in,
                              void* d_out, int out_size, void* d_ws, size_t ws_size,
                              hipStream_t stream) {
  const float* x   = (const float*)d_in[0];
  const float* Wq  = (const float*)d_in[1];
  const float* bq  = (const float*)d_in[2];
  const float* Wk  = (const float*)d_in[3];
  const float* bk  = (const float*)d_in[4];
  const float* Wv  = (const float*)d_in[5];
  const float* bv  = (const float*)d_in[6];
  const float* Wo  = (const float*)d_in[7];
  const float* bo  = (const float*)d_in[8];
  const float* lam = (const float*)d_in[9];
  const float* gw  = (const float*)d_in[10];
  const float* gb  = (const float*)d_in[11];
  float* out = (float*)d_out;

  char* p = (char*)d_ws;
  auto alloc = [&](size_t bytes) {
    char* r = p;
    p += (bytes + 255) & ~(size_t)255;
    return r;
  };
  u16* xb     = (u16*)alloc((size_t)M_PAD * 768 * 2);   // also reused as ctxbuf
  u16* wtqkv  = (u16*)alloc((size_t)3840 * 768 * 2);
  u16* wot    = (u16*)alloc((size_t)768 * 768 * 2);
  u16* q1b    = (u16*)alloc((size_t)192 * 577 * 64 * 2);
  u16* q2b    = (u16*)alloc((size_t)192 * 577 * 64 * 2);
  u16* k1b    = (u16*)alloc((size_t)192 * 577 * 64 * 2);
  u16* k2b    = (u16*)alloc((size_t)192 * 577 * 64 * 2);
  u16* vtb    = (u16*)alloc((size_t)192 * 64 * VT_STRIDE * 2);
  u16* ctxt   = (u16*)alloc((size_t)192 * 64 * S_LEN * 2);
  u16* ctxbuf = xb;   // alias: xb is dead after the QKV GEMM; keeps ws ~108 MB

  prep_x<<<(M_PAD * 768 / 8 + 255) / 256, 256, 0, stream>>>(x, xb);
  prep_w<<<3456, 256, 0, stream>>>(Wq, Wk, Wv, Wo, wtqkv, wot);

  gemm_bf16<<<dim3(73, 30), 256, 0, stream>>>(xb, wtqkv, 3840, 1,
      nullptr, nullptr, q1b, q2b, k1b, k2b, vtb, bq, bk, bv);

  attn<<<dim3(192, 10), 256, 0, stream>>>(q1b, q2b, k1b, k2b, vtb, ctxt, lam);

  gnorm<<<192, 256, 0, stream>>>(ctxt, ctxbuf, gw, gb);

  gemm_bf16<<<dim3(73, 6), 256, 0, stream>>>(ctxbuf, wot, 768, 0,
      out, bo, nullptr, nullptr, nullptr, nullptr, nullptr, nullptr, nullptr, nullptr);
}

// Round 8
// 469.097 us; speedup vs baseline: 1.0607x; 1.0607x over previous
//
#include <hip/hip_runtime.h>
#include <hip/hip_bf16.h>
#include <stdint.h>

typedef unsigned short u16;
typedef __attribute__((ext_vector_type(8))) short bf16x8;
typedef __attribute__((ext_vector_type(4))) float f32x4;

#define S_LEN 577
#define DMODEL 768
#define NHEAD 12
#define DH 64
#define BATCH 16
#define M_ROWS (BATCH * S_LEN)   /* 9232 */
#define M_PAD 9344               /* 73 * 128 */
#define VT_STRIDE 640            /* padded S so 16B frag loads stay aligned */

__device__ __forceinline__ u16 f2bu(float f) {
  uint32_t u = __float_as_uint(f);
  u += 0x7FFFu + ((u >> 16) & 1u);      // RNE; inputs are finite
  return (u16)(u >> 16);
}
__device__ __forceinline__ float bu2f(u16 b) {
  return __uint_as_float(((uint32_t)b) << 16);
}
// async global->LDS, 16B per lane; LDS dest = wave-uniform base + lane*16
__device__ __forceinline__ void gl2lds16(const u16* g, u16* l) {
  __builtin_amdgcn_global_load_lds(
      (const __attribute__((address_space(1))) unsigned int*)g,
      (__attribute__((address_space(3))) unsigned int*)l, 16, 0, 0);
}

// ---------------- prep: x fp32 -> bf16 [M_PAD,768], pad rows zeroed ----------
__global__ __launch_bounds__(256) void prep_x(const float* __restrict__ x,
                                              u16* __restrict__ xb) {
  int e = (blockIdx.x * 256 + threadIdx.x) * 8;
  u16 o[8];
  if (e < M_ROWS * DMODEL) {
    float4 f0 = *(const float4*)(x + e);
    float4 f1 = *(const float4*)(x + e + 4);
    o[0] = f2bu(f0.x); o[1] = f2bu(f0.y); o[2] = f2bu(f0.z); o[3] = f2bu(f0.w);
    o[4] = f2bu(f1.x); o[5] = f2bu(f1.y); o[6] = f2bu(f1.z); o[7] = f2bu(f1.w);
  } else {
#pragma unroll
    for (int i = 0; i < 8; ++i) o[i] = 0;
  }
  *(uint4*)(xb + e) = *(const uint4*)o;
}

// ------------- prep: weights fp32 [K,N] -> bf16 transposed [N,K], tiled ------
// wtqkv rows: [0,1536)=Wq^T, [1536,3072)=Wk^T, [3072,3840)=Wv^T ; wot = Wo^T
__global__ __launch_bounds__(256) void prep_w(
    const float* __restrict__ Wq, const float* __restrict__ Wk,
    const float* __restrict__ Wv, const float* __restrict__ Wo,
    u16* __restrict__ wtqkv, u16* __restrict__ wot) {
  __shared__ u16 tile[32][33];
  int blk = blockIdx.x;
  const float* W; int N; u16* dst; int rowbase;
  if (blk < 1152)      { W = Wq; N = 1536; dst = wtqkv; rowbase = 0; }
  else if (blk < 2304) { W = Wk; N = 1536; dst = wtqkv; rowbase = 1536; blk -= 1152; }
  else if (blk < 2880) { W = Wv; N = 768;  dst = wtqkv; rowbase = 3072; blk -= 2304; }
  else                 { W = Wo; N = 768;  dst = wot;   rowbase = 0;    blk -= 2880; }
  const int ntiles = N >> 5;
  const int tk = blk / ntiles, tn = blk - tk * ntiles;
  const int c = threadIdx.x & 31, r0 = threadIdx.x >> 5;
#pragma unroll
  for (int i = 0; i < 4; ++i) {
    int r = i * 8 + r0;
    tile[r][c] = f2bu(W[(size_t)(tk * 32 + r) * N + tn * 32 + c]);
  }
  __syncthreads();
#pragma unroll
  for (int i = 0; i < 4; ++i) {
    int r = i * 8 + r0;
    dst[(size_t)(rowbase + tn * 32 + r) * 768 + tk * 32 + c] = tile[c][r];
  }
}

// ---------------- bf16 MFMA GEMM: C[M,N] = A[M,768] * Bt[N,768]^T ------------
// m97 structure: global_load_lds width-16 staging into unpadded 128x32 tiles.
// mode 0: out fp32 [M_ROWS,N] + biasO[n]  (output projection)
// mode 1: scatter -> q1/q2/k1/k2 [B,H,S,64] bf16, v -> vt [B,H,64,640]
__global__ __launch_bounds__(256, 2) void gemm_bf16(
    const u16* __restrict__ A, const u16* __restrict__ Bt, int N, int mode,
    float* __restrict__ outF, const float* __restrict__ biasO,
    u16* __restrict__ q1p, u16* __restrict__ q2p,
    u16* __restrict__ k1p, u16* __restrict__ k2p, u16* __restrict__ vtp,
    const float* __restrict__ bq, const float* __restrict__ bk,
    const float* __restrict__ bvp) {
  __shared__ u16 lA[128 * 32];
  __shared__ u16 lB[128 * 32];
  const int t = threadIdx.x;
  const int lane = t & 63, wave = t >> 6;
  const int quad = lane >> 4, l16 = lane & 15;
  const int wm = wave & 1, wn = wave >> 1;
  const int m0 = blockIdx.x * 128;
  const int n0 = blockIdx.y * 128;

  f32x4 zero = {0.f, 0.f, 0.f, 0.f};
  f32x4 acc[4][4];
  for (int i = 0; i < 4; ++i) for (int j = 0; j < 4; ++j) acc[i][j] = zero;

  // staging: wave w owns rows w*32..w*32+31 (2 chunks of 16 rows);
  // lane -> row base + lane/4, col (lane%4)*8  (LDS offset == lane*16 B)
  const int srow = wave * 32 + (lane >> 2);
  const int scol = (lane & 3) * 8;
  const u16* gA = A + (size_t)(m0 + srow) * 768 + scol;
  const u16* gB = Bt + (size_t)(n0 + srow) * 768 + scol;
  u16* sA = lA + wave * 1024;   // wave-uniform LDS base
  u16* sB = lB + wave * 1024;

  for (int k0 = 0; k0 < 768; k0 += 32) {
    gl2lds16(gA + k0, sA);
    gl2lds16(gA + k0 + 16 * 768, sA + 512);
    gl2lds16(gB + k0, sB);
    gl2lds16(gB + k0 + 16 * 768, sB + 512);
    __syncthreads();
    bf16x8 af[4], bfr[4];
#pragma unroll
    for (int i = 0; i < 4; ++i)
      af[i] = *(const bf16x8*)(lA + (wm * 64 + i * 16 + l16) * 32 + quad * 8);
#pragma unroll
    for (int j = 0; j < 4; ++j)
      bfr[j] = *(const bf16x8*)(lB + (wn * 64 + j * 16 + l16) * 32 + quad * 8);
#pragma unroll
    for (int i = 0; i < 4; ++i)
#pragma unroll
      for (int j = 0; j < 4; ++j)
        acc[i][j] = __builtin_amdgcn_mfma_f32_16x16x32_bf16(af[i], bfr[j], acc[i][j], 0, 0, 0);
    __syncthreads();
  }

#pragma unroll
  for (int i = 0; i < 4; ++i) {
#pragma unroll
    for (int j = 0; j < 4; ++j) {
      int n = n0 + wn * 64 + j * 16 + l16;
#pragma unroll
      for (int r = 0; r < 4; ++r) {
        int m = m0 + wm * 64 + i * 16 + quad * 4 + r;
        if (m >= M_ROWS) continue;
        float v = acc[i][j][r];
        if (mode == 0) {
          outF[(size_t)m * N + n] = v + biasO[n];
        } else {
          int b = m / 577;
          int s = m - b * 577;
          if (n < 1536) {
            int ch = (n < 768) ? n : (n - 768);
            u16* dst = (n < 768) ? q1p : q2p;
            dst[(((size_t)b * 12 + (ch >> 6)) * 577 + s) * 64 + (ch & 63)] = f2bu(v + bq[n]);
          } else if (n < 3072) {
            int nn = n - 1536;
            int ch = (nn < 768) ? nn : (nn - 768);
            u16* dst = (nn < 768) ? k1p : k2p;
            dst[(((size_t)b * 12 + (ch >> 6)) * 577 + s) * 64 + (ch & 63)] = f2bu(v + bk[nn]);
          } else {
            int ch = n - 3072;
            vtp[(((size_t)b * 12 + (ch >> 6)) * 64 + (ch & 63)) * VT_STRIDE + s] = f2bu(v + bvp[ch]);
          }
        }
      }
    }
  }
}

// ---------------- flash-style differential attention (no-max softmax) --------
// SINGLE-WAVE workgroups: waves never shared data anyway; 64-thread blocks
// remove the 4-wave residency quantum -> ~2.5x more resident waves for
// latency hiding. grid: (bh=192, qtile=37); one wave = 16 q-rows; KV blocks
// of 32 (R5 structure, which measured 201us vs 221us for 64-KV batching).
__global__ __launch_bounds__(64, 4) void attn(
    const u16* __restrict__ q1, const u16* __restrict__ q2,
    const u16* __restrict__ k1, const u16* __restrict__ k2,
    const u16* __restrict__ vt, u16* __restrict__ ctx_t,
    const float* __restrict__ lam_p) {
  __shared__ u16 pls[2][16 * 40];   // P staging (D-layout -> A-layout)
  const int bh = blockIdx.x;
  const int lane = threadIdx.x & 63;
  const int quad = lane >> 4, l16 = lane & 15;
  const int q0 = blockIdx.y * 16;

  const float lam = lam_p[0];
  const float CEXP = 0.125f * 1.44269504f;   // scale * log2(e), folded
  const size_t qkbase = (size_t)bh * S_LEN * DH;

  int qr = q0 + l16; if (qr > 576) qr = 576;   // clamp tail (results discarded)
  bf16x8 q1f[2], q2f[2];
#pragma unroll
  for (int c = 0; c < 2; ++c) {
    q1f[c] = *(const bf16x8*)(q1 + qkbase + (size_t)qr * 64 + c * 32 + quad * 8);
    q2f[c] = *(const bf16x8*)(q2 + qkbase + (size_t)qr * 64 + c * 32 + quad * 8);
  }

  f32x4 zero = {0.f, 0.f, 0.f, 0.f};
  f32x4 O1[4], O2[4];
  float l1[4], l2[4];
#pragma unroll
  for (int i = 0; i < 4; ++i) { O1[i] = zero; O2[i] = zero; l1[i] = 0.f; l2[i] = 0.f; }

  u16* p1w = &pls[0][0];
  u16* p2w = &pls[1][0];
  const size_t vbase = (size_t)bh * 64 * VT_STRIDE;

  for (int kb = 0; kb < 19; ++kb) {
    const int kv0 = kb * 32;
    bf16x8 k1f[2][2], k2f[2][2];
#pragma unroll
    for (int tt = 0; tt < 2; ++tt) {
      int kr = kv0 + tt * 16 + l16; if (kr > 576) kr = 576;
      size_t off = qkbase + (size_t)kr * 64 + quad * 8;
      k1f[tt][0] = *(const bf16x8*)(k1 + off);
      k1f[tt][1] = *(const bf16x8*)(k1 + off + 32);
      k2f[tt][0] = *(const bf16x8*)(k2 + off);
      k2f[tt][1] = *(const bf16x8*)(k2 + off + 32);
    }
    f32x4 s1[2], s2[2];
#pragma unroll
    for (int tt = 0; tt < 2; ++tt) {
      s1[tt] = __builtin_amdgcn_mfma_f32_16x16x32_bf16(q1f[0], k1f[tt][0], zero, 0, 0, 0);
      s1[tt] = __builtin_amdgcn_mfma_f32_16x16x32_bf16(q1f[1], k1f[tt][1], s1[tt], 0, 0, 0);
      s2[tt] = __builtin_amdgcn_mfma_f32_16x16x32_bf16(q2f[0], k2f[tt][0], zero, 0, 0, 0);
      s2[tt] = __builtin_amdgcn_mfma_f32_16x16x32_bf16(q2f[1], k2f[tt][1], s2[tt], 0, 0, 0);
    }
    bool ok0 = (kv0 + l16) < S_LEN;
    bool ok1 = (kv0 + 16 + l16) < S_LEN;
    bf16x8 vf[4];
#pragma unroll
    for (int tt = 0; tt < 4; ++tt)
      vf[tt] = *(const bf16x8*)(vt + vbase + (size_t)(tt * 16 + l16) * VT_STRIDE + kv0 + quad * 8);
#pragma unroll
    for (int i = 0; i < 4; ++i) {
      float p10 = ok0 ? exp2f(s1[0][i] * CEXP) : 0.f;
      float p11 = ok1 ? exp2f(s1[1][i] * CEXP) : 0.f;
      float p20 = ok0 ? exp2f(s2[0][i] * CEXP) : 0.f;
      float p21 = ok1 ? exp2f(s2[1][i] * CEXP) : 0.f;
      l1[i] += p10 + p11;
      l2[i] += p20 + p21;
      // truncating bf16 convert (cheap; ~0.1% bias, well under budget)
      p1w[(quad * 4 + i) * 40 + l16]      = (u16)(__float_as_uint(p10) >> 16);
      p1w[(quad * 4 + i) * 40 + l16 + 16] = (u16)(__float_as_uint(p11) >> 16);
      p2w[(quad * 4 + i) * 40 + l16]      = (u16)(__float_as_uint(p20) >> 16);
      p2w[(quad * 4 + i) * 40 + l16 + 16] = (u16)(__float_as_uint(p21) >> 16);
    }
    bf16x8 p1a = *(const bf16x8*)(p1w + l16 * 40 + quad * 8);
    bf16x8 p2a = *(const bf16x8*)(p2w + l16 * 40 + quad * 8);
#pragma unroll
    for (int tt = 0; tt < 4; ++tt) {
      O1[tt] = __builtin_amdgcn_mfma_f32_16x16x32_bf16(p1a, vf[tt], O1[tt], 0, 0, 0);
      O2[tt] = __builtin_amdgcn_mfma_f32_16x16x32_bf16(p2a, vf[tt], O2[tt], 0, 0, 0);
    }
  }
  // reduce partial row-sums across the quad's 16 lanes
#pragma unroll
  for (int d = 1; d < 16; d <<= 1)
#pragma unroll
    for (int i = 0; i < 4; ++i) {
      l1[i] += __shfl_xor(l1[i], d);
      l2[i] += __shfl_xor(l2[i], d);
    }
  float inv1[4], inv2[4];
#pragma unroll
  for (int i = 0; i < 4; ++i) { inv1[i] = 1.f / l1[i]; inv2[i] = 1.f / l2[i]; }
#pragma unroll
  for (int tt = 0; tt < 4; ++tt) {
    size_t cb = ((size_t)bh * 64 + tt * 16 + l16) * S_LEN;
#pragma unroll
    for (int i = 0; i < 4; ++i) {
      int s = q0 + quad * 4 + i;
      if (s < S_LEN)
        ctx_t[cb + s] = f2bu(O1[tt][i] * inv1[i] - lam * O2[tt][i] * inv2[i]);
    }
  }
}

// ---------------- GroupNorm over (b,h): Dh*S elements, then affine ----------
// ctx_t [B,H,64,S] -> context flat [B][D*S] (== reference's reinterpret trick)
__global__ __launch_bounds__(256) void gnorm(
    const u16* __restrict__ ctx_t, u16* __restrict__ context,
    const float* __restrict__ gw, const float* __restrict__ gb) {
  const int bh = blockIdx.x;
  const int h = bh % 12;
  const int NEL = 64 * S_LEN;          // 36928
  const int NV = NEL / 8;              // 4616
  const u16* src = ctx_t + (size_t)bh * NEL;
  float sum = 0.f, sq = 0.f;
  for (int v = threadIdx.x; v < NV; v += 256) {
    uint4 raw = *(const uint4*)(src + v * 8);
    uint32_t w[4] = {raw.x, raw.y, raw.z, raw.w};
#pragma unroll
    for (int j = 0; j < 4; ++j) {
      float f0 = bu2f((u16)(w[j] & 0xffff));
      float f1 = bu2f((u16)(w[j] >> 16));
      sum += f0 + f1; sq += f0 * f0 + f1 * f1;
    }
  }
#pragma unroll
  for (int d = 1; d < 64; d <<= 1) {
    sum += __shfl_xor(sum, d);
    sq += __shfl_xor(sq, d);
  }
  __shared__ float rs[4], rq[4];
  __shared__ float wv[64], bv2[64];
  int wave = threadIdx.x >> 6;
  if ((threadIdx.x & 63) == 0) { rs[wave] = sum; rq[wave] = sq; }
  __syncthreads();
  float ts = rs[0] + rs[1] + rs[2] + rs[3];
  float tq = rq[0] + rq[1] + rq[2] + rq[3];
  const float Ninv = 1.0f / (float)NEL;
  float mu = ts * Ninv;
  float var = tq * Ninv - mu * mu;
  float rstd = rsqrtf(var + 1e-5f);
  if (threadIdx.x < 64) {
    float w = gw[h * 64 + threadIdx.x] * rstd;
    wv[threadIdx.x] = w;
    bv2[threadIdx.x] = gb[h * 64 + threadIdx.x] - mu * w;
  }
  __syncthreads();
  u16* dst = context + (size_t)bh * NEL;   // b*(768*577) + h*(64*577)
  for (int v = threadIdx.x; v < NV; v += 256) {
    uint4 raw = *(const uint4*)(src + v * 8);
    uint32_t w[4] = {raw.x, raw.y, raw.z, raw.w};
    int base = v * 8;
    int d0 = base / 577;
    int r0 = base - d0 * 577;
    u16 o[8];
#pragma unroll
    for (int j = 0; j < 4; ++j) {
#pragma unroll
      for (int e = 0; e < 2; ++e) {
        int ii = j * 2 + e;
        int dd = (r0 + ii >= 577) ? d0 + 1 : d0;
        float f = bu2f((u16)(e == 0 ? (w[j] & 0xffff) : (w[j] >> 16)));
        o[ii] = f2bu(f * wv[dd] + bv2[dd]);
      }
    }
    *(uint4*)(dst + base) = *(const uint4*)o;
  }
}

extern "C" void kernel_launch(void* const* d_in, const int* in_sizes, int n_in,
                              void* d_out, int out_size, void* d_ws, size_t ws_size,
                              hipStream_t stream) {
  const float* x   = (const float*)d_in[0];
  const float* Wq  = (const float*)d_in[1];
  const float* bq  = (const float*)d_in[2];
  const float* Wk  = (const float*)d_in[3];
  const float* bk  = (const float*)d_in[4];
  const float* Wv  = (const float*)d_in[5];
  const float* bv  = (const float*)d_in[6];
  const float* Wo  = (const float*)d_in[7];
  const float* bo  = (const float*)d_in[8];
  const float* lam = (const float*)d_in[9];
  const float* gw  = (const float*)d_in[10];
  const float* gb  = (const float*)d_in[11];
  float* out = (float*)d_out;

  char* p = (char*)d_ws;
  auto alloc = [&](size_t bytes) {
    char* r = p;
    p += (bytes + 255) & ~(size_t)255;
    return r;
  };
  u16* xb     = (u16*)alloc((size_t)M_PAD * 768 * 2);   // also reused as ctxbuf
  u16* wtqkv  = (u16*)alloc((size_t)3840 * 768 * 2);
  u16* wot    = (u16*)alloc((size_t)768 * 768 * 2);
  u16* q1b    = (u16*)alloc((size_t)192 * 577 * 64 * 2);
  u16* q2b    = (u16*)alloc((size_t)192 * 577 * 64 * 2);
  u16* k1b    = (u16*)alloc((size_t)192 * 577 * 64 * 2);
  u16* k2b    = (u16*)alloc((size_t)192 * 577 * 64 * 2);
  u16* vtb    = (u16*)alloc((size_t)192 * 64 * VT_STRIDE * 2);
  u16* ctxt   = (u16*)alloc((size_t)192 * 64 * S_LEN * 2);
  u16* ctxbuf = xb;   // alias: xb is dead after the QKV GEMM; keeps ws ~108 MB

  prep_x<<<(M_PAD * 768 / 8 + 255) / 256, 256, 0, stream>>>(x, xb);
  prep_w<<<3456, 256, 0, stream>>>(Wq, Wk, Wv, Wo, wtqkv, wot);

  gemm_bf16<<<dim3(73, 30), 256, 0, stream>>>(xb, wtqkv, 3840, 1,
      nullptr, nullptr, q1b, q2b, k1b, k2b, vtb, bq, bk, bv);

  attn<<<dim3(192, 37), 64, 0, stream>>>(q1b, q2b, k1b, k2b, vtb, ctxt, lam);

  gnorm<<<192, 256, 0, stream>>>(ctxt, ctxbuf, gw, gb);

  gemm_bf16<<<dim3(73, 6), 256, 0, stream>>>(ctxbuf, wot, 768, 0,
      out, bo, nullptr, nullptr, nullptr, nullptr, nullptr, nullptr, nullptr, nullptr);
}